// Round 7
// baseline (278.183 us; speedup 1.0000x reference)
//
#include <hip/hip_runtime.h>
#include <math.h>

#define Cdim   256
#define Ssp    8192      // D*H*W
#define Npts   65536
#define NCODES 1024
#define BETA   0.25f
#define MT     64        // points per GEMM block
#define NKC    48        // K-chunks of 16 (K=768 split: [zh|zh|zl] x [eh|el|eh])
#define ESCALE 8192.0f   // keep el out of f16-subnormal truncation
#define WS_NEED (65536 + (size_t)786432 * 2)

typedef _Float16 f16;
typedef f16   half8  __attribute__((ext_vector_type(8)));
typedef float f32x16 __attribute__((ext_vector_type(16)));

#define MFMA16(A, B, C) __builtin_amdgcn_mfma_f32_32x32x16_f16(A, B, C, 0, 0, 0)

// ---------------- embed norms ----------------
__global__ __launch_bounds__(256) void enorm_kernel(const float* __restrict__ embed,
                                                    float* __restrict__ enorm) {
    int j = blockIdx.x * 256 + threadIdx.x;
    if (j >= NCODES) return;
    const float4* row = reinterpret_cast<const float4*>(embed + (size_t)j * Cdim);
    float s = 0.f;
#pragma unroll 8
    for (int c4 = 0; c4 < Cdim / 4; ++c4) {
        float4 v = row[c4];
        s += v.x * v.x + v.y * v.y + v.z * v.z + v.w * v.w;
    }
    enorm[j] = s;
}

// ---------------- prep: split embed into f16 hi/lo, chunk-tiled ----------------
// Bws: [kc=48][code=1024][k'=16] f16. k = kc*16+k'; k 0..255 -> eh, 256..511 -> el,
// 512..767 -> eh. Scaled by ESCALE. (verified rounds 5/6)
__global__ __launch_bounds__(256) void prep_kernel(const float* __restrict__ embed,
                                                   f16* __restrict__ Bws) {
    int tid = blockIdx.x * 256 + threadIdx.x;
    int o4 = tid * 4;
    int kc = o4 >> 14;
    int r  = o4 & 16383;
    int j  = r >> 4;
    int k0 = r & 15;
#pragma unroll
    for (int i = 0; i < 4; ++i) {
        int k = kc * 16 + k0 + i;
        int c = k & 255;
        float ev = embed[j * 256 + c] * ESCALE;
        f16 eh = (f16)ev;
        f16 v  = (k >= 256 && k < 512) ? (f16)(ev - (float)eh) : eh;
        Bws[o4 + i] = v;
    }
}

// ---------------- MFMA GEMM + fused argmin + fused epilogue (v3) ----------------
// 256 thr / 4 waves, 64 points x 1024 codes, K=768 as 2 code-halves.
// A = [zh|zl] 64KB LDS (XOR-swizzled granules), staged via NON-TEMPORAL z loads
// (keeps B L2-resident). 2-chunk body: 4 A ds_reads up front, B loads for k+2/k+3
// issued between the two 8-MFMA groups (>=1-body prefetch distance). Epilogue
// fused: z_q gather-write (nt stores) + loss = sum(best score).
__global__ __launch_bounds__(256, 2) void vq_gemm(const float* __restrict__ z,
                                                  const f16* __restrict__ Bws,
                                                  const float* __restrict__ embed,
                                                  const float* __restrict__ enorm,
                                                  float* __restrict__ out_zq,
                                                  float* __restrict__ out_idx,
                                                  float* __restrict__ loss_acc,
                                                  float* __restrict__ counts) {
    __shared__ __attribute__((aligned(16))) f16 As[MT * 512];   // 64 KB
    __shared__ float en_s[NCODES];                              // 4 KB
    __shared__ float znp[256];
    __shared__ float zn_s[MT];
    __shared__ float redv[8 * MT];                              // (jh,w) x row
    __shared__ int   redi[8 * MT];
    __shared__ int   idxf[MT];

    const int t  = threadIdx.x;
    const int l  = t & 63;
    const int w  = t >> 6;
    const int ln = l & 31;
    const int kb = l >> 5;
    const int n0 = blockIdx.x * MT;
    const int b  = n0 >> 13;
    const int s0 = n0 & 8191;

    // ---- stage A (zh granules 0..31, zl granules 32..63, swizzle g^=(p&7)) ----
    {
        const int p = t & 63;
        const int q = t >> 6;                 // c-quad, 64 c each
        const float* zb = z + (size_t)b * ((size_t)Cdim * Ssp) + s0;
        float zsq = 0.f;
#pragma unroll
        for (int gi = 0; gi < 8; ++gi) {
            const int c0 = q * 64 + gi * 8;
            half8 hh, ll;
#pragma unroll
            for (int u = 0; u < 8; ++u) {     // c ascending -> zsq order == rounds 2/5/6
                float zv = __builtin_nontemporal_load(zb + (size_t)(c0 + u) * Ssp + p);
                zsq += zv * zv;
                f16 zh = (f16)zv;
                hh[u] = zh;
                ll[u] = (f16)(zv - (float)zh);
            }
            const int g0 = c0 >> 3;           // 0..31
            *(half8*)&As[p * 512 + 8 * (g0 ^ (p & 7))]        = hh;
            *(half8*)&As[p * 512 + 8 * ((32 + g0) ^ (p & 7))] = ll;
        }
        znp[q * 64 + p] = zsq;
    }
    for (int i = t; i < NCODES; i += 256) en_s[i] = enorm[i];
    __syncthreads();
    if (t < MT) zn_s[t] = ((znp[t] + znp[64 + t]) + znp[128 + t]) + znp[192 + t];
    __syncthreads();

    // ---- two code-halves of 512; wave w owns 128 codes per half ----
#pragma unroll 1
    for (int jh = 0; jh < 2; ++jh) {
        f32x16 acc[2][4] = {};
        const f16* bbase = Bws + (size_t)(jh * 512 + w * 128 + ln) * 16 + kb * 8;

        // prologue: chunks 0 and 1
        half8 bA0 = *(const half8*)(bbase);
        half8 bA1 = *(const half8*)(bbase + 512);
        half8 bA2 = *(const half8*)(bbase + 1024);
        half8 bA3 = *(const half8*)(bbase + 1536);
        const f16* s1 = bbase + 16384;
        half8 bB0 = *(const half8*)(s1);
        half8 bB1 = *(const half8*)(s1 + 512);
        half8 bB2 = *(const half8*)(s1 + 1024);
        half8 bB3 = *(const half8*)(s1 + 1536);

#pragma unroll 1
        for (int kc = 0; kc < NKC; kc += 2) {
            // granule ids for chunks kc (A) and kc+1 (B); region boundaries (16,32)
            // are even so both chunks share a region
            const int base = (kc < 16) ? (2 * kc) : (kc < 32) ? (2 * (kc - 16))
                                                              : (32 + 2 * (kc - 32));
            const int ggA = base + kb;
            const int ggB = base + 2 + kb;
            half8 aA0 = *(const half8*)&As[ln * 512 + 8 * (ggA ^ (ln & 7))];
            half8 aA1 = *(const half8*)&As[(32 + ln) * 512 + 8 * (ggA ^ (ln & 7))];
            half8 aB0 = *(const half8*)&As[ln * 512 + 8 * (ggB ^ (ln & 7))];
            half8 aB1 = *(const half8*)&As[(32 + ln) * 512 + 8 * (ggB ^ (ln & 7))];

            // MFMA group A (chunk kc)
            acc[0][0] = MFMA16(aA0, bA0, acc[0][0]);
            acc[1][0] = MFMA16(aA1, bA0, acc[1][0]);
            acc[0][1] = MFMA16(aA0, bA1, acc[0][1]);
            acc[1][1] = MFMA16(aA1, bA1, acc[1][1]);
            acc[0][2] = MFMA16(aA0, bA2, acc[0][2]);
            acc[1][2] = MFMA16(aA1, bA2, acc[1][2]);
            acc[0][3] = MFMA16(aA0, bA3, acc[0][3]);
            acc[1][3] = MFMA16(aA1, bA3, acc[1][3]);

            // prefetch chunk kc+2 into bA (consumed next body, >=1 group away)
            {
                const int pf = (kc + 2 < NKC) ? kc + 2 : NKC - 1;
                const f16* src = bbase + (size_t)pf * 16384;
                bA0 = *(const half8*)(src);
                bA1 = *(const half8*)(src + 512);
                bA2 = *(const half8*)(src + 1024);
                bA3 = *(const half8*)(src + 1536);
            }

            // MFMA group B (chunk kc+1)
            acc[0][0] = MFMA16(aB0, bB0, acc[0][0]);
            acc[1][0] = MFMA16(aB1, bB0, acc[1][0]);
            acc[0][1] = MFMA16(aB0, bB1, acc[0][1]);
            acc[1][1] = MFMA16(aB1, bB1, acc[1][1]);
            acc[0][2] = MFMA16(aB0, bB2, acc[0][2]);
            acc[1][2] = MFMA16(aB1, bB2, acc[1][2]);
            acc[0][3] = MFMA16(aB0, bB3, acc[0][3]);
            acc[1][3] = MFMA16(aB1, bB3, acc[1][3]);

            // prefetch chunk kc+3 into bB
            {
                const int pf = (kc + 3 < NKC) ? kc + 3 : NKC - 1;
                const f16* src = bbase + (size_t)pf * 16384;
                bB0 = *(const half8*)(src);
                bB1 = *(const half8*)(src + 512);
                bB2 = *(const half8*)(src + 1024);
                bB3 = *(const half8*)(src + 1536);
            }
        }

        // ---- scores + per-half argmin. C layout: col=lane&31,
        //      row=(reg&3)+8*(reg>>2)+4*(lane>>5)  (verified rounds 5/6) ----
        const int h = l >> 5;
#pragma unroll
        for (int mm = 0; mm < 2; ++mm) {
#pragma unroll
            for (int rg = 0; rg < 16; ++rg) {
                const int row = mm * 32 + (rg & 3) + 8 * (rg >> 2) + 4 * h;
                const float znv = zn_s[row];
                float bv = 3.0e38f; int bi = 0;
#pragma unroll
                for (int nn = 0; nn < 4; ++nn) {
                    const int col = jh * 512 + w * 128 + nn * 32 + ln;
                    float k1 = znv + en_s[col];
                    float sc = k1 - acc[mm][nn][rg] * (2.0f / ESCALE);
                    if (sc < bv) { bv = sc; bi = col; }
                }
#pragma unroll
                for (int off = 1; off < 32; off <<= 1) {
                    float ov = __shfl_xor(bv, off, 64);
                    int   oi = __shfl_xor(bi, off, 64);
                    if (ov < bv || (ov == bv && oi < bi)) { bv = ov; bi = oi; }
                }
                if (ln == 0) {
                    redv[(jh * 4 + w) * MT + row] = bv;
                    redi[(jh * 4 + w) * MT + row] = bi;
                }
            }
        }
    }
    __syncthreads();

    // ---- final argmin + index/count/loss (loss = sum of best scores) ----
    if (t < MT) {
        float bv = redv[t]; int bi = redi[t];
#pragma unroll
        for (int s = 1; s < 8; ++s) {
            float ov = redv[s * MT + t]; int oi = redi[s * MT + t];
            if (ov < bv || (ov == bv && oi < bi)) { bv = ov; bi = oi; }
        }
        out_idx[n0 + t] = (float)bi;
        idxf[t] = bi;
        atomicAdd(&counts[bi], 1.0f);
        float lsum = bv;
#pragma unroll
        for (int off = 32; off > 0; off >>= 1) lsum += __shfl_down(lsum, off, 64);
        if (t == 0) atomicAdd(loss_acc, lsum);
    }
    __syncthreads();

    // ---- fused z_q write: gather embed row (L2-hot), nt strided stores ----
    {
        const int p     = t & 63;
        const int cbase = t >> 6;
        const int myidx = idxf[p];
        const float4* erow4 = reinterpret_cast<const float4*>(embed + (size_t)myidx * Cdim);
        float* ob = out_zq + (size_t)b * ((size_t)Cdim * Ssp) + s0 + p;
#pragma unroll 4
        for (int pass = 0; pass < 16; ++pass) {
            int c = cbase * 64 + pass * 4;
            float4 e = erow4[c >> 2];
            __builtin_nontemporal_store(e.x, ob + (size_t)(c + 0) * Ssp);
            __builtin_nontemporal_store(e.y, ob + (size_t)(c + 1) * Ssp);
            __builtin_nontemporal_store(e.z, ob + (size_t)(c + 2) * Ssp);
            __builtin_nontemporal_store(e.w, ob + (size_t)(c + 3) * Ssp);
        }
    }
}

// ================= fallback (round-4 verified kernel, used if ws too small) =================
#define PTS 64
#define CT  128
#define KC  32
__global__ __launch_bounds__(256, 2) void vq_main_fb(const float* __restrict__ z,
                                                     const float* __restrict__ embed,
                                                     const float* __restrict__ enorm,
                                                     float* __restrict__ out_zq,
                                                     float* __restrict__ out_idx,
                                                     float* __restrict__ loss_acc,
                                                     float* __restrict__ counts) {
    __shared__ __attribute__((aligned(16))) float smem[Cdim * PTS + KC * CT];
    float* zt = smem;
    float* et = smem + Cdim * PTS;
    const int t  = threadIdx.x;
    const int n0 = blockIdx.x * PTS;
    const int b  = n0 >> 13;
    const int s0 = n0 & 8191;
    const float* zb = z + (size_t)b * Cdim * Ssp + s0;
    {
        const int p4 = (t & 15) * 4, crow = t >> 4;
#pragma unroll
        for (int it = 0; it < 16; ++it) {
            int c = it * 16 + crow;
            float4 v = *reinterpret_cast<const float4*>(zb + (size_t)c * Ssp + p4);
            *reinterpret_cast<float4*>(&zt[c * PTS + p4]) = v;
        }
    }
    __syncthreads();
    {
        const int p = t & 63, qq = t >> 6;
        float sacc = 0.f;
#pragma unroll 8
        for (int c = qq * 64; c < qq * 64 + 64; ++c) { float v = zt[c * PTS + p]; sacc += v * v; }
        et[qq * 64 + p] = sacc;
    }
    __syncthreads();
    const int pg = t & 15, jg = t >> 4;
    const int p0 = pg * 4;
    float zn[4];
#pragma unroll
    for (int i = 0; i < 4; ++i) {
        int p = p0 + i;
        zn[i] = ((et[p] + et[64 + p]) + et[128 + p]) + et[192 + p];
    }
    float bestv[4] = {3.0e38f, 3.0e38f, 3.0e38f, 3.0e38f};
    int   besti[4] = {0, 0, 0, 0};
    const int dj = t >> 3, q = t & 7;
    const int sw_st = (q & 3) << 3;
    for (int jt = 0; jt < NCODES / CT; ++jt) {
        const int J0 = jt * CT;
        float acc[4][8];
#pragma unroll
        for (int i = 0; i < 4; ++i)
#pragma unroll
            for (int m = 0; m < 8; ++m) acc[i][m] = 0.f;
        for (int ks = 0; ks < Cdim / KC; ++ks) {
            const int cc0 = ks * KC;
            __syncthreads();
#pragma unroll
            for (int i = 0; i < 4; ++i) {
                const int jrel = dj + 32 * i;
                const float4 v = *reinterpret_cast<const float4*>(
                    embed + (size_t)(J0 + jrel) * Cdim + cc0 + q * 4);
                const int c0 = q * 4;
                const int jsw = jrel ^ sw_st;
                et[(c0 + 0) * CT + jsw] = v.x;
                et[(c0 + 1) * CT + jsw] = v.y;
                et[(c0 + 2) * CT + jsw] = v.z;
                et[(c0 + 3) * CT + jsw] = v.w;
            }
            __syncthreads();
#pragma unroll 4
            for (int c = 0; c < KC; ++c) {
                const float4 zp = *reinterpret_cast<const float4*>(&zt[(cc0 + c) * PTS + p0]);
                const int jb = (jg * 8) ^ (((c >> 2) & 3) << 3);
                const float4 ea = *reinterpret_cast<const float4*>(&et[c * CT + jb]);
                const float4 eb = *reinterpret_cast<const float4*>(&et[c * CT + jb + 4]);
                const float zc[4] = {zp.x, zp.y, zp.z, zp.w};
                const float ec[8] = {ea.x, ea.y, ea.z, ea.w, eb.x, eb.y, eb.z, eb.w};
#pragma unroll
                for (int i = 0; i < 4; ++i)
#pragma unroll
                    for (int m = 0; m < 8; ++m) acc[i][m] += zc[i] * ec[m];
            }
        }
#pragma unroll
        for (int m = 0; m < 8; ++m) {
            const int cid = J0 + jg * 8 + m;
            const float en = enorm[cid];
#pragma unroll
            for (int i = 0; i < 4; ++i) {
                float k1 = zn[i] + en;
                float sc = k1 - 2.0f * acc[i][m];
                if (sc < bestv[i]) { bestv[i] = sc; besti[i] = cid; }
            }
        }
    }
    __syncthreads();
    float* rv = et; int* ri = (int*)(et + 1024); int* idxf = (int*)(et + 2048);
#pragma unroll
    for (int i = 0; i < 4; ++i) { int p = p0 + i; rv[p * 16 + jg] = bestv[i]; ri[p * 16 + jg] = besti[i]; }
    __syncthreads();
    if (t < PTS) {
        int p = t;
        float bv = rv[p * 16]; int bi = ri[p * 16];
        for (int g = 1; g < 16; ++g) {
            float v = rv[p * 16 + g]; int ii = ri[p * 16 + g];
            if (v < bv || (v == bv && ii < bi)) { bv = v; bi = ii; }
        }
        idxf[p] = bi;
        out_idx[n0 + p] = (float)bi;
        atomicAdd(&counts[bi], 1.0f);
    }
    __syncthreads();
    float lsum = 0.f;
    {
        const int p = t & 63, cbase = t >> 6;
        const int myidx = idxf[p];
        const float4* erow4 = reinterpret_cast<const float4*>(embed + (size_t)myidx * Cdim);
        float* ob = out_zq + (size_t)b * Cdim * Ssp + s0 + p;
#pragma unroll 4
        for (int pass = 0; pass < 16; ++pass) {
            int c = cbase * 64 + pass * 4;
            float4 e = erow4[c >> 2];
            ob[(size_t)(c + 0) * Ssp] = e.x;
            ob[(size_t)(c + 1) * Ssp] = e.y;
            ob[(size_t)(c + 2) * Ssp] = e.z;
            ob[(size_t)(c + 3) * Ssp] = e.w;
            float d0 = zt[(c + 0) * PTS + p] - e.x;
            float d1 = zt[(c + 1) * PTS + p] - e.y;
            float d2 = zt[(c + 2) * PTS + p] - e.z;
            float d3 = zt[(c + 3) * PTS + p] - e.w;
            lsum += d0 * d0 + d1 * d1 + d2 * d2 + d3 * d3;
        }
    }
#pragma unroll
    for (int off = 32; off > 0; off >>= 1) lsum += __shfl_down(lsum, off, 64);
    if ((t & 63) == 0) atomicAdd(loss_acc, lsum);
}

// ---------------- finalize ----------------
__global__ __launch_bounds__(1024) void vq_final(const float* __restrict__ counts,
                                                 const float* __restrict__ loss_acc,
                                                 float* __restrict__ out_loss,
                                                 float* __restrict__ out_perp) {
    __shared__ float red[16];
    int t = threadIdx.x;
    float cnt = counts[t];
    float avg = cnt * (1.0f / (float)Npts);
    float term = avg * logf(avg + 1e-10f);
#pragma unroll
    for (int off = 32; off > 0; off >>= 1) term += __shfl_down(term, off, 64);
    if ((t & 63) == 0) red[t >> 6] = term;
    __syncthreads();
    if (t == 0) {
        float s = 0.f;
        for (int i = 0; i < 16; ++i) s += red[i];
        *out_perp = expf(-s);
        *out_loss = BETA * loss_acc[0] * (1.0f / 16777216.0f);
    }
}

extern "C" void kernel_launch(void* const* d_in, const int* in_sizes, int n_in,
                              void* d_out, int out_size, void* d_ws, size_t ws_size,
                              hipStream_t stream) {
    const float* z     = (const float*)d_in[0];
    const float* embed = (const float*)d_in[1];

    float* ws       = (float*)d_ws;
    float* loss_acc = ws;            // [0]
    float* counts   = ws + 64;       // [1024]
    float* enorm    = ws + 2048;     // [1024]

    float* out_zq   = (float*)d_out;
    float* out_idx  = out_zq + (size_t)Npts * Cdim;
    float* out_loss = out_idx + Npts;
    float* out_perp = out_loss + 1;

    hipMemsetAsync(d_ws, 0, 2048 * sizeof(float), stream);
    enorm_kernel<<<NCODES / 256, 256, 0, stream>>>(embed, enorm);

    if (ws_size >= WS_NEED) {
        f16* Bws = (f16*)((char*)d_ws + 65536);
        prep_kernel<<<768, 256, 0, stream>>>(embed, Bws);
        vq_gemm<<<Npts / MT, 256, 0, stream>>>(z, Bws, embed, enorm, out_zq,
                                               out_idx, loss_acc, counts);
    } else {
        vq_main_fb<<<Npts / PTS, 256, 0, stream>>>(z, embed, enorm, out_zq, out_idx,
                                                   loss_acc, counts);
    }
    vq_final<<<1, 1024, 0, stream>>>(counts, loss_acc, out_loss, out_perp);
}

// Round 8
// 234.802 us; speedup vs baseline: 1.1848x; 1.1848x over previous
//
#include <hip/hip_runtime.h>
#include <math.h>

#define Cdim   256
#define Ssp    8192      // D*H*W
#define Npts   65536
#define NCODES 1024
#define BETA   0.25f
#define MT     64        // points per GEMM block
#define NKC    48        // K-chunks of 16 (K=768 split: [zh|zh|zl] x [eh|el|eh])
#define ESCALE 8192.0f   // keep el out of f16-subnormal truncation
#define WS_NEED (65536 + (size_t)786432 * 2)

typedef _Float16 f16;
typedef f16   half8  __attribute__((ext_vector_type(8)));
typedef float f32x16 __attribute__((ext_vector_type(16)));

#define MFMA16(A, B, C) __builtin_amdgcn_mfma_f32_32x32x16_f16(A, B, C, 0, 0, 0)

// ---------------- embed norms ----------------
__global__ __launch_bounds__(256) void enorm_kernel(const float* __restrict__ embed,
                                                    float* __restrict__ enorm) {
    int j = blockIdx.x * 256 + threadIdx.x;
    if (j >= NCODES) return;
    const float4* row = reinterpret_cast<const float4*>(embed + (size_t)j * Cdim);
    float s = 0.f;
#pragma unroll 8
    for (int c4 = 0; c4 < Cdim / 4; ++c4) {
        float4 v = row[c4];
        s += v.x * v.x + v.y * v.y + v.z * v.z + v.w * v.w;
    }
    enorm[j] = s;
}

// ---------------- prep: split embed into f16 hi/lo, chunk-tiled ----------------
// Bws: [kc=48][code=1024][k'=16] f16. k = kc*16+k'; k 0..255 -> eh, 256..511 -> el,
// 512..767 -> eh. Scaled by ESCALE. (verified rounds 5/6/7)
__global__ __launch_bounds__(256) void prep_kernel(const float* __restrict__ embed,
                                                   f16* __restrict__ Bws) {
    int tid = blockIdx.x * 256 + threadIdx.x;
    int o4 = tid * 4;
    int kc = o4 >> 14;
    int r  = o4 & 16383;
    int j  = r >> 4;
    int k0 = r & 15;
#pragma unroll
    for (int i = 0; i < 4; ++i) {
        int k = kc * 16 + k0 + i;
        int c = k & 255;
        float ev = embed[j * 256 + c] * ESCALE;
        f16 eh = (f16)ev;
        f16 v  = (k >= 256 && k < 512) ? (f16)(ev - (float)eh) : eh;
        Bws[o4 + i] = v;
    }
}

// granule id (region boundaries 16/32 verified rounds 5-7)
#define GG(k) (((k) < 16) ? (2 * (k) + kb) : ((k) < 32) ? (2 * ((k) - 16) + kb) \
                                                        : (32 + 2 * ((k) - 32) + kb))

// One K-chunk body: prefetch next chunk's A (LDS), 8 MFMAs, prefetch B(kc+3).
#define ABODY(kcv, BB, AC0, AC1, AN0, AN1)                               \
    {                                                                    \
        const int kcn = ((kcv) + 1 < NKC) ? (kcv) + 1 : NKC - 1;         \
        const int ggn = GG(kcn);                                         \
        AN0 = *(const half8*)&As[ln * 512 + 8 * (ggn ^ (ln & 7))];       \
        AN1 = *(const half8*)&As[(32 + ln) * 512 + 8 * (ggn ^ (ln & 7))];\
        acc[0][0] = MFMA16(AC0, BB[0], acc[0][0]);                       \
        acc[1][0] = MFMA16(AC1, BB[0], acc[1][0]);                       \
        acc[0][1] = MFMA16(AC0, BB[1], acc[0][1]);                       \
        acc[1][1] = MFMA16(AC1, BB[1], acc[1][1]);                       \
        acc[0][2] = MFMA16(AC0, BB[2], acc[0][2]);                       \
        acc[1][2] = MFMA16(AC1, BB[2], acc[1][2]);                       \
        acc[0][3] = MFMA16(AC0, BB[3], acc[0][3]);                       \
        acc[1][3] = MFMA16(AC1, BB[3], acc[1][3]);                       \
        const int pf = ((kcv) + 3 < NKC) ? (kcv) + 3 : NKC - 1;          \
        const f16* src = bbase + (size_t)pf * 16384;                     \
        BB[0] = *(const half8*)(src);                                    \
        BB[1] = *(const half8*)(src + 512);                              \
        BB[2] = *(const half8*)(src + 1024);                             \
        BB[3] = *(const half8*)(src + 1536);                             \
    }

// ---------------- MFMA GEMM + fused argmin + loss (v4) ----------------
// 256 thr / 4 waves, 64 points x 1024 codes, K=768 as 2 code-halves.
// A = [zh|zl] 64KB LDS (XOR-swizzled), nt z staging. B: 3 rotating chunk-bufs
// (depth-2 prefetch); A: double-buffered one chunk ahead. Loss = sum(best score).
__global__ __launch_bounds__(256, 2) void vq_gemm(const float* __restrict__ z,
                                                  const f16* __restrict__ Bws,
                                                  const float* __restrict__ enorm,
                                                  float* __restrict__ out_idx,
                                                  float* __restrict__ loss_acc,
                                                  float* __restrict__ counts) {
    __shared__ __attribute__((aligned(16))) f16 As[MT * 512];   // 64 KB
    __shared__ float en_s[NCODES];                              // 4 KB
    __shared__ float znp[256];
    __shared__ float zn_s[MT];
    __shared__ float redv[8 * MT];                              // (jh,w) x row
    __shared__ int   redi[8 * MT];

    const int t  = threadIdx.x;
    const int l  = t & 63;
    const int w  = t >> 6;
    const int ln = l & 31;
    const int kb = l >> 5;
    const int n0 = blockIdx.x * MT;
    const int b  = n0 >> 13;
    const int s0 = n0 & 8191;

    // ---- stage A (zh granules 0..31, zl 32..63, swizzle g^=(p&7)); nt z loads ----
    {
        const int p = t & 63;
        const int q = t >> 6;
        const float* zb = z + (size_t)b * ((size_t)Cdim * Ssp) + s0;
        float zsq = 0.f;
#pragma unroll
        for (int gi = 0; gi < 8; ++gi) {
            const int c0 = q * 64 + gi * 8;
            half8 hh, ll;
#pragma unroll
            for (int u = 0; u < 8; ++u) {     // c ascending -> zsq order == rounds 2/5/6
                float zv = __builtin_nontemporal_load(zb + (size_t)(c0 + u) * Ssp + p);
                zsq += zv * zv;
                f16 zh = (f16)zv;
                hh[u] = zh;
                ll[u] = (f16)(zv - (float)zh);
            }
            const int g0 = c0 >> 3;
            *(half8*)&As[p * 512 + 8 * (g0 ^ (p & 7))]        = hh;
            *(half8*)&As[p * 512 + 8 * ((32 + g0) ^ (p & 7))] = ll;
        }
        znp[q * 64 + p] = zsq;
    }
    for (int i = t; i < NCODES; i += 256) en_s[i] = enorm[i];
    __syncthreads();
    if (t < MT) zn_s[t] = ((znp[t] + znp[64 + t]) + znp[128 + t]) + znp[192 + t];
    __syncthreads();

    // ---- two code-halves of 512; wave w owns 128 codes per half ----
#pragma unroll 1
    for (int jh = 0; jh < 2; ++jh) {
        f32x16 acc[2][4] = {};
        const f16* bbase = Bws + (size_t)(jh * 512 + w * 128 + ln) * 16 + kb * 8;

        // B preload: chunks 0,1,2 into 3 rotating buffers
        half8 b0[4], b1[4], b2[4];
#pragma unroll
        for (int i = 0; i < 4; ++i) b0[i] = *(const half8*)(bbase + i * 512);
#pragma unroll
        for (int i = 0; i < 4; ++i) b1[i] = *(const half8*)(bbase + 16384 + i * 512);
#pragma unroll
        for (int i = 0; i < 4; ++i) b2[i] = *(const half8*)(bbase + 32768 + i * 512);

        // A preload: chunk 0
        half8 aC0, aC1, aD0, aD1;
        {
            const int gg0 = GG(0);
            aC0 = *(const half8*)&As[ln * 512 + 8 * (gg0 ^ (ln & 7))];
            aC1 = *(const half8*)&As[(32 + ln) * 512 + 8 * (gg0 ^ (ln & 7))];
        }

#pragma unroll 1
        for (int kc = 0; kc < NKC; kc += 6) {
            ABODY(kc + 0, b0, aC0, aC1, aD0, aD1)
            ABODY(kc + 1, b1, aD0, aD1, aC0, aC1)
            ABODY(kc + 2, b2, aC0, aC1, aD0, aD1)
            ABODY(kc + 3, b0, aD0, aD1, aC0, aC1)
            ABODY(kc + 4, b1, aC0, aC1, aD0, aD1)
            ABODY(kc + 5, b2, aD0, aD1, aC0, aC1)
        }

        // ---- scores + per-half argmin. C layout: col=lane&31,
        //      row=(reg&3)+8*(reg>>2)+4*(lane>>5)  (verified rounds 5-7) ----
        const int h = l >> 5;
#pragma unroll
        for (int mm = 0; mm < 2; ++mm) {
#pragma unroll
            for (int rg = 0; rg < 16; ++rg) {
                const int row = mm * 32 + (rg & 3) + 8 * (rg >> 2) + 4 * h;
                const float znv = zn_s[row];
                float bv = 3.0e38f; int bi = 0;
#pragma unroll
                for (int nn = 0; nn < 4; ++nn) {
                    const int col = jh * 512 + w * 128 + nn * 32 + ln;
                    float k1 = znv + en_s[col];
                    float sc = k1 - acc[mm][nn][rg] * (2.0f / ESCALE);
                    if (sc < bv) { bv = sc; bi = col; }
                }
#pragma unroll
                for (int off = 1; off < 32; off <<= 1) {
                    float ov = __shfl_xor(bv, off, 64);
                    int   oi = __shfl_xor(bi, off, 64);
                    if (ov < bv || (ov == bv && oi < bi)) { bv = ov; bi = oi; }
                }
                if (ln == 0) {
                    redv[(jh * 4 + w) * MT + row] = bv;
                    redi[(jh * 4 + w) * MT + row] = bi;
                }
            }
        }
    }
    __syncthreads();

    // ---- final argmin; index/count; loss = sum of best scores ----
    if (t < MT) {
        float bv = redv[t]; int bi = redi[t];
#pragma unroll
        for (int s = 1; s < 8; ++s) {
            float ov = redv[s * MT + t]; int oi = redi[s * MT + t];
            if (ov < bv || (ov == bv && oi < bi)) { bv = ov; bi = oi; }
        }
        out_idx[n0 + t] = (float)bi;
        atomicAdd(&counts[bi], 1.0f);
        float lsum = bv;
#pragma unroll
        for (int off = 32; off > 0; off >>= 1) lsum += __shfl_down(lsum, off, 64);
        if (t == 0) atomicAdd(loss_acc, lsum);
    }
}

// ---------------- epilogue: z_q gather-write only (no z read, no loss) ----------------
__global__ __launch_bounds__(256) void vq_epi(const float* __restrict__ embed,
                                              const float* __restrict__ out_idx,
                                              float* __restrict__ out_zq) {
    const int n = blockIdx.x * 256 + threadIdx.x;
    const int b = n >> 13, s = n & 8191;
    const int idx = (int)out_idx[n];
    const float4* er = reinterpret_cast<const float4*>(embed + (size_t)idx * Cdim);
    float* oq = out_zq + (size_t)b * ((size_t)Cdim * Ssp) + s;
#pragma unroll 4
    for (int c4 = 0; c4 < Cdim / 4; ++c4) {
        float4 e = er[c4];                   // per-lane gather, L2-hot (embed = 1MB)
        const int c = c4 * 4;
        __builtin_nontemporal_store(e.x, oq + (size_t)(c + 0) * Ssp);
        __builtin_nontemporal_store(e.y, oq + (size_t)(c + 1) * Ssp);
        __builtin_nontemporal_store(e.z, oq + (size_t)(c + 2) * Ssp);
        __builtin_nontemporal_store(e.w, oq + (size_t)(c + 3) * Ssp);
    }
}

// ================= fallback (round-4 verified kernel, used if ws too small) =================
#define PTS 64
#define CT  128
#define KC  32
__global__ __launch_bounds__(256, 2) void vq_main_fb(const float* __restrict__ z,
                                                     const float* __restrict__ embed,
                                                     const float* __restrict__ enorm,
                                                     float* __restrict__ out_zq,
                                                     float* __restrict__ out_idx,
                                                     float* __restrict__ loss_acc,
                                                     float* __restrict__ counts) {
    __shared__ __attribute__((aligned(16))) float smem[Cdim * PTS + KC * CT];
    float* zt = smem;
    float* et = smem + Cdim * PTS;
    const int t  = threadIdx.x;
    const int n0 = blockIdx.x * PTS;
    const int b  = n0 >> 13;
    const int s0 = n0 & 8191;
    const float* zb = z + (size_t)b * Cdim * Ssp + s0;
    {
        const int p4 = (t & 15) * 4, crow = t >> 4;
#pragma unroll
        for (int it = 0; it < 16; ++it) {
            int c = it * 16 + crow;
            float4 v = *reinterpret_cast<const float4*>(zb + (size_t)c * Ssp + p4);
            *reinterpret_cast<float4*>(&zt[c * PTS + p4]) = v;
        }
    }
    __syncthreads();
    {
        const int p = t & 63, qq = t >> 6;
        float sacc = 0.f;
#pragma unroll 8
        for (int c = qq * 64; c < qq * 64 + 64; ++c) { float v = zt[c * PTS + p]; sacc += v * v; }
        et[qq * 64 + p] = sacc;
    }
    __syncthreads();
    const int pg = t & 15, jg = t >> 4;
    const int p0 = pg * 4;
    float zn[4];
#pragma unroll
    for (int i = 0; i < 4; ++i) {
        int p = p0 + i;
        zn[i] = ((et[p] + et[64 + p]) + et[128 + p]) + et[192 + p];
    }
    float bestv[4] = {3.0e38f, 3.0e38f, 3.0e38f, 3.0e38f};
    int   besti[4] = {0, 0, 0, 0};
    const int dj = t >> 3, q = t & 7;
    const int sw_st = (q & 3) << 3;
    for (int jt = 0; jt < NCODES / CT; ++jt) {
        const int J0 = jt * CT;
        float acc[4][8];
#pragma unroll
        for (int i = 0; i < 4; ++i)
#pragma unroll
            for (int m = 0; m < 8; ++m) acc[i][m] = 0.f;
        for (int ks = 0; ks < Cdim / KC; ++ks) {
            const int cc0 = ks * KC;
            __syncthreads();
#pragma unroll
            for (int i = 0; i < 4; ++i) {
                const int jrel = dj + 32 * i;
                const float4 v = *reinterpret_cast<const float4*>(
                    embed + (size_t)(J0 + jrel) * Cdim + cc0 + q * 4);
                const int c0 = q * 4;
                const int jsw = jrel ^ sw_st;
                et[(c0 + 0) * CT + jsw] = v.x;
                et[(c0 + 1) * CT + jsw] = v.y;
                et[(c0 + 2) * CT + jsw] = v.z;
                et[(c0 + 3) * CT + jsw] = v.w;
            }
            __syncthreads();
#pragma unroll 4
            for (int c = 0; c < KC; ++c) {
                const float4 zp = *reinterpret_cast<const float4*>(&zt[(cc0 + c) * PTS + p0]);
                const int jb = (jg * 8) ^ (((c >> 2) & 3) << 3);
                const float4 ea = *reinterpret_cast<const float4*>(&et[c * CT + jb]);
                const float4 eb = *reinterpret_cast<const float4*>(&et[c * CT + jb + 4]);
                const float zc[4] = {zp.x, zp.y, zp.z, zp.w};
                const float ec[8] = {ea.x, ea.y, ea.z, ea.w, eb.x, eb.y, eb.z, eb.w};
#pragma unroll
                for (int i = 0; i < 4; ++i)
#pragma unroll
                    for (int m = 0; m < 8; ++m) acc[i][m] += zc[i] * ec[m];
            }
        }
#pragma unroll
        for (int m = 0; m < 8; ++m) {
            const int cid = J0 + jg * 8 + m;
            const float en = enorm[cid];
#pragma unroll
            for (int i = 0; i < 4; ++i) {
                float k1 = zn[i] + en;
                float sc = k1 - 2.0f * acc[i][m];
                if (sc < bestv[i]) { bestv[i] = sc; besti[i] = cid; }
            }
        }
    }
    __syncthreads();
    float* rv = et; int* ri = (int*)(et + 1024); int* idxf = (int*)(et + 2048);
#pragma unroll
    for (int i = 0; i < 4; ++i) { int p = p0 + i; rv[p * 16 + jg] = bestv[i]; ri[p * 16 + jg] = besti[i]; }
    __syncthreads();
    if (t < PTS) {
        int p = t;
        float bv = rv[p * 16]; int bi = ri[p * 16];
        for (int g = 1; g < 16; ++g) {
            float v = rv[p * 16 + g]; int ii = ri[p * 16 + g];
            if (v < bv || (v == bv && ii < bi)) { bv = v; bi = ii; }
        }
        idxf[p] = bi;
        out_idx[n0 + p] = (float)bi;
        atomicAdd(&counts[bi], 1.0f);
    }
    __syncthreads();
    float lsum = 0.f;
    {
        const int p = t & 63, cbase = t >> 6;
        const int myidx = idxf[p];
        const float4* erow4 = reinterpret_cast<const float4*>(embed + (size_t)myidx * Cdim);
        float* ob = out_zq + (size_t)b * Cdim * Ssp + s0 + p;
#pragma unroll 4
        for (int pass = 0; pass < 16; ++pass) {
            int c = cbase * 64 + pass * 4;
            float4 e = erow4[c >> 2];
            ob[(size_t)(c + 0) * Ssp] = e.x;
            ob[(size_t)(c + 1) * Ssp] = e.y;
            ob[(size_t)(c + 2) * Ssp] = e.z;
            ob[(size_t)(c + 3) * Ssp] = e.w;
            float d0 = zt[(c + 0) * PTS + p] - e.x;
            float d1 = zt[(c + 1) * PTS + p] - e.y;
            float d2 = zt[(c + 2) * PTS + p] - e.z;
            float d3 = zt[(c + 3) * PTS + p] - e.w;
            lsum += d0 * d0 + d1 * d1 + d2 * d2 + d3 * d3;
        }
    }
#pragma unroll
    for (int off = 32; off > 0; off >>= 1) lsum += __shfl_down(lsum, off, 64);
    if ((t & 63) == 0) atomicAdd(loss_acc, lsum);
}

// ---------------- finalize ----------------
__global__ __launch_bounds__(1024) void vq_final(const float* __restrict__ counts,
                                                 const float* __restrict__ loss_acc,
                                                 float* __restrict__ out_loss,
                                                 float* __restrict__ out_perp) {
    __shared__ float red[16];
    int t = threadIdx.x;
    float cnt = counts[t];
    float avg = cnt * (1.0f / (float)Npts);
    float term = avg * logf(avg + 1e-10f);
#pragma unroll
    for (int off = 32; off > 0; off >>= 1) term += __shfl_down(term, off, 64);
    if ((t & 63) == 0) red[t >> 6] = term;
    __syncthreads();
    if (t == 0) {
        float s = 0.f;
        for (int i = 0; i < 16; ++i) s += red[i];
        *out_perp = expf(-s);
        *out_loss = BETA * loss_acc[0] * (1.0f / 16777216.0f);
    }
}

extern "C" void kernel_launch(void* const* d_in, const int* in_sizes, int n_in,
                              void* d_out, int out_size, void* d_ws, size_t ws_size,
                              hipStream_t stream) {
    const float* z     = (const float*)d_in[0];
    const float* embed = (const float*)d_in[1];

    float* ws       = (float*)d_ws;
    float* loss_acc = ws;            // [0]
    float* counts   = ws + 64;       // [1024]
    float* enorm    = ws + 2048;     // [1024]

    float* out_zq   = (float*)d_out;
    float* out_idx  = out_zq + (size_t)Npts * Cdim;
    float* out_loss = out_idx + Npts;
    float* out_perp = out_loss + 1;

    hipMemsetAsync(d_ws, 0, 2048 * sizeof(float), stream);
    enorm_kernel<<<NCODES / 256, 256, 0, stream>>>(embed, enorm);

    if (ws_size >= WS_NEED) {
        f16* Bws = (f16*)((char*)d_ws + 65536);
        prep_kernel<<<768, 256, 0, stream>>>(embed, Bws);
        vq_gemm<<<Npts / MT, 256, 0, stream>>>(z, Bws, enorm, out_idx,
                                               loss_acc, counts);
        vq_epi<<<Npts / 256, 256, 0, stream>>>(embed, out_idx, out_zq);
    } else {
        vq_main_fb<<<Npts / PTS, 256, 0, stream>>>(z, embed, enorm, out_zq, out_idx,
                                                   loss_acc, counts);
    }
    vq_final<<<1, 1024, 0, stream>>>(counts, loss_acc, out_loss, out_perp);
}

// Round 9
// 207.785 us; speedup vs baseline: 1.3388x; 1.1300x over previous
//
#include <hip/hip_runtime.h>
#include <math.h>

#define Cdim   256
#define Ssp    8192      // D*H*W
#define Npts   65536
#define NCODES 1024
#define BETA   0.25f
#define MT     128       // points per GEMM block (v5: doubled -> halves B traffic)
#define NKC    48        // K-chunks of 16 (K=768 split: [zh|zh|zl] x [eh|el|eh])
#define ESCALE 8192.0f   // keep el out of f16-subnormal truncation
#define WS_NEED (65536 + (size_t)786432 * 2)

typedef _Float16 f16;
typedef f16   half8  __attribute__((ext_vector_type(8)));
typedef float f32x16 __attribute__((ext_vector_type(16)));

#define MFMA16(A, B, C) __builtin_amdgcn_mfma_f32_32x32x16_f16(A, B, C, 0, 0, 0)

// ---------------- embed norms ----------------
__global__ __launch_bounds__(256) void enorm_kernel(const float* __restrict__ embed,
                                                    float* __restrict__ enorm) {
    int j = blockIdx.x * 256 + threadIdx.x;
    if (j >= NCODES) return;
    const float4* row = reinterpret_cast<const float4*>(embed + (size_t)j * Cdim);
    float s = 0.f;
#pragma unroll 8
    for (int c4 = 0; c4 < Cdim / 4; ++c4) {
        float4 v = row[c4];
        s += v.x * v.x + v.y * v.y + v.z * v.z + v.w * v.w;
    }
    enorm[j] = s;
}

// ---------------- prep: split embed into f16 hi/lo, chunk-tiled ----------------
// Bws: [kc=48][code=1024][k'=16] f16. k = kc*16+k'; k 0..255 -> eh, 256..511 -> el,
// 512..767 -> eh. Scaled by ESCALE. (verified rounds 5-8)
__global__ __launch_bounds__(256) void prep_kernel(const float* __restrict__ embed,
                                                   f16* __restrict__ Bws) {
    int tid = blockIdx.x * 256 + threadIdx.x;
    int o4 = tid * 4;
    int kc = o4 >> 14;
    int r  = o4 & 16383;
    int j  = r >> 4;
    int k0 = r & 15;
#pragma unroll
    for (int i = 0; i < 4; ++i) {
        int k = kc * 16 + k0 + i;
        int c = k & 255;
        float ev = embed[j * 256 + c] * ESCALE;
        f16 eh = (f16)ev;
        f16 v  = (k >= 256 && k < 512) ? (f16)(ev - (float)eh) : eh;
        Bws[o4 + i] = v;
    }
}

// granule id (region boundaries 16/32 verified rounds 5-8)
#define GG(k) (((k) < 16) ? (2 * (k) + kb) : ((k) < 32) ? (2 * ((k) - 16) + kb) \
                                                        : (32 + 2 * ((k) - 32) + kb))

// ---------------- MFMA GEMM + fused argmin + loss (v5: MT=128, 8 waves) ----------------
// 512 thr / 8 waves (2 m-wave-groups x 4 n-wave-groups), 128 points x 1024 codes,
// K=768 as 2 code-halves. A = [zh|zl] 128KB LDS (XOR-swizzled), read-only after one
// barrier; no barriers in K-loop. B direct global->reg (L2-hot), 1-deep prefetch
// (r6's measured-best schedule). Per-wave: 8 MFMAs/chunk => prefetch distance
// ~2.5x L2 latency. Loss = sum of best scores (no z re-read anywhere downstream).
__global__ __launch_bounds__(512, 2) void vq_gemm(const float* __restrict__ z,
                                                  const f16* __restrict__ Bws,
                                                  const float* __restrict__ enorm,
                                                  float* __restrict__ out_idx,
                                                  float* __restrict__ loss_acc,
                                                  float* __restrict__ counts) {
    __shared__ __attribute__((aligned(16))) f16 As[MT * 512];   // 128 KB
    __shared__ float en_s[NCODES];                              // 4 KB
    __shared__ float znp[4 * MT];                               // 2 KB
    __shared__ float zn_s[MT];                                  // 0.5 KB
    __shared__ float redv[8 * MT];                              // 4 KB (jh,wn) x row
    __shared__ int   redi[8 * MT];                              // 4 KB

    const int t  = threadIdx.x;
    const int l  = t & 63;
    const int w  = t >> 6;            // 0..7
    const int wm = w >> 2;            // 0..1 : rows [wm*64, wm*64+64)
    const int wn = w & 3;             // 0..3 : codes [wn*128, +128) per half
    const int ln = l & 31;
    const int kb = l >> 5;
    const int n0 = blockIdx.x * MT;
    const int b  = n0 >> 13;
    const int s0 = n0 & 8191;

    // ---- stage A (zh granules 0..31, zl 32..63, swizzle g^=(p&7)) ----
    {
        const int p = t & 127;        // point row
        const int q = t >> 7;         // c-quad, 64 c each (same 64-c tree as r2/r6)
        const float* zb = z + (size_t)b * ((size_t)Cdim * Ssp) + s0;
        float zsq = 0.f;
#pragma unroll
        for (int gi = 0; gi < 8; ++gi) {
            const int c0 = q * 64 + gi * 8;
            half8 hh, ll;
#pragma unroll
            for (int u = 0; u < 8; ++u) {     // c ascending -> zsq order == rounds 2/5-8
                float zv = zb[(size_t)(c0 + u) * Ssp + p];
                zsq += zv * zv;
                f16 zh = (f16)zv;
                hh[u] = zh;
                ll[u] = (f16)(zv - (float)zh);
            }
            const int g0 = c0 >> 3;           // 0..31
            *(half8*)&As[p * 512 + 8 * (g0 ^ (p & 7))]        = hh;
            *(half8*)&As[p * 512 + 8 * ((32 + g0) ^ (p & 7))] = ll;
        }
        znp[q * MT + p] = zsq;
    }
    for (int i = t; i < NCODES; i += 512) en_s[i] = enorm[i];
    __syncthreads();
    if (t < MT)
        zn_s[t] = ((znp[t] + znp[MT + t]) + znp[2 * MT + t]) + znp[3 * MT + t];
    __syncthreads();

    // ---- two code-halves of 512; wave (wm,wn) owns rows [wm*64,+64) x codes
    //      [jh*512+wn*128, +128) ----
#pragma unroll 1
    for (int jh = 0; jh < 2; ++jh) {
        f32x16 acc[2][4] = {};
        const f16* bbase = Bws + (size_t)(jh * 512 + wn * 128 + ln) * 16 + kb * 8;

        half8 b0 = *(const half8*)(bbase);
        half8 b1 = *(const half8*)(bbase + 512);
        half8 b2 = *(const half8*)(bbase + 1024);
        half8 b3 = *(const half8*)(bbase + 1536);

        const int rowA = wm * 64 + ln;
#pragma unroll 2
        for (int kc = 0; kc < NKC; ++kc) {
            const int gg  = GG(kc);
            const int gsw = 8 * (gg ^ (ln & 7));
            half8 a0 = *(const half8*)&As[rowA * 512 + gsw];
            half8 a1 = *(const half8*)&As[(rowA + 32) * 512 + gsw];

            half8 n0r = b0, n1 = b1, n2 = b2, n3 = b3;
            if (kc + 1 < NKC) {
                const f16* src = bbase + (size_t)(kc + 1) * 16384;
                n0r = *(const half8*)(src);
                n1  = *(const half8*)(src + 512);
                n2  = *(const half8*)(src + 1024);
                n3  = *(const half8*)(src + 1536);
            }
            acc[0][0] = MFMA16(a0, b0, acc[0][0]);
            acc[1][0] = MFMA16(a1, b0, acc[1][0]);
            acc[0][1] = MFMA16(a0, b1, acc[0][1]);
            acc[1][1] = MFMA16(a1, b1, acc[1][1]);
            acc[0][2] = MFMA16(a0, b2, acc[0][2]);
            acc[1][2] = MFMA16(a1, b2, acc[1][2]);
            acc[0][3] = MFMA16(a0, b3, acc[0][3]);
            acc[1][3] = MFMA16(a1, b3, acc[1][3]);
            b0 = n0r; b1 = n1; b2 = n2; b3 = n3;
        }

        // ---- scores + per-half argmin. C layout: col=lane&31,
        //      row=(reg&3)+8*(reg>>2)+4*(lane>>5)  (verified rounds 5-8) ----
        const int h = l >> 5;
#pragma unroll
        for (int mm = 0; mm < 2; ++mm) {
#pragma unroll
            for (int rg = 0; rg < 16; ++rg) {
                const int row = wm * 64 + mm * 32 + (rg & 3) + 8 * (rg >> 2) + 4 * h;
                const float znv = zn_s[row];
                float bv = 3.0e38f; int bi = 0;
#pragma unroll
                for (int nn = 0; nn < 4; ++nn) {
                    const int col = jh * 512 + wn * 128 + nn * 32 + ln;
                    float k1 = znv + en_s[col];
                    float sc = k1 - acc[mm][nn][rg] * (2.0f / ESCALE);
                    if (sc < bv) { bv = sc; bi = col; }
                }
#pragma unroll
                for (int off = 1; off < 32; off <<= 1) {
                    float ov = __shfl_xor(bv, off, 64);
                    int   oi = __shfl_xor(bi, off, 64);
                    if (ov < bv || (ov == bv && oi < bi)) { bv = ov; bi = oi; }
                }
                if (ln == 0) {
                    redv[(jh * 4 + wn) * MT + row] = bv;
                    redi[(jh * 4 + wn) * MT + row] = bi;
                }
            }
        }
    }
    __syncthreads();

    // ---- final argmin; index/count; loss = sum of best scores ----
    if (t < MT) {
        float bv = redv[t]; int bi = redi[t];
#pragma unroll
        for (int s = 1; s < 8; ++s) {
            float ov = redv[s * MT + t]; int oi = redi[s * MT + t];
            if (ov < bv || (ov == bv && oi < bi)) { bv = ov; bi = oi; }
        }
        out_idx[n0 + t] = (float)bi;
        atomicAdd(&counts[bi], 1.0f);
        float lsum = bv;
#pragma unroll
        for (int off = 32; off > 0; off >>= 1) lsum += __shfl_down(lsum, off, 64);
        if ((t & 63) == 0) atomicAdd(loss_acc, lsum);
    }
}

// ---------------- epilogue: z_q gather-write only (no z read, no loss) ----------------
__global__ __launch_bounds__(256) void vq_epi(const float* __restrict__ embed,
                                              const float* __restrict__ out_idx,
                                              float* __restrict__ out_zq) {
    const int n = blockIdx.x * 256 + threadIdx.x;
    const int b = n >> 13, s = n & 8191;
    const int idx = (int)out_idx[n];
    const float4* er = reinterpret_cast<const float4*>(embed + (size_t)idx * Cdim);
    float* oq = out_zq + (size_t)b * ((size_t)Cdim * Ssp) + s;
#pragma unroll 4
    for (int c4 = 0; c4 < Cdim / 4; ++c4) {
        float4 e = er[c4];                   // per-lane gather, L2-hot (embed = 1MB)
        const int c = c4 * 4;
        __builtin_nontemporal_store(e.x, oq + (size_t)(c + 0) * Ssp);
        __builtin_nontemporal_store(e.y, oq + (size_t)(c + 1) * Ssp);
        __builtin_nontemporal_store(e.z, oq + (size_t)(c + 2) * Ssp);
        __builtin_nontemporal_store(e.w, oq + (size_t)(c + 3) * Ssp);
    }
}

// ================= fallback (round-4 verified kernel, used if ws too small) =================
#define PTS 64
#define CT  128
#define KC  32
__global__ __launch_bounds__(256, 2) void vq_main_fb(const float* __restrict__ z,
                                                     const float* __restrict__ embed,
                                                     const float* __restrict__ enorm,
                                                     float* __restrict__ out_zq,
                                                     float* __restrict__ out_idx,
                                                     float* __restrict__ loss_acc,
                                                     float* __restrict__ counts) {
    __shared__ __attribute__((aligned(16))) float smem[Cdim * PTS + KC * CT];
    float* zt = smem;
    float* et = smem + Cdim * PTS;
    const int t  = threadIdx.x;
    const int n0 = blockIdx.x * PTS;
    const int b  = n0 >> 13;
    const int s0 = n0 & 8191;
    const float* zb = z + (size_t)b * Cdim * Ssp + s0;
    {
        const int p4 = (t & 15) * 4, crow = t >> 4;
#pragma unroll
        for (int it = 0; it < 16; ++it) {
            int c = it * 16 + crow;
            float4 v = *reinterpret_cast<const float4*>(zb + (size_t)c * Ssp + p4);
            *reinterpret_cast<float4*>(&zt[c * PTS + p4]) = v;
        }
    }
    __syncthreads();
    {
        const int p = t & 63, qq = t >> 6;
        float sacc = 0.f;
#pragma unroll 8
        for (int c = qq * 64; c < qq * 64 + 64; ++c) { float v = zt[c * PTS + p]; sacc += v * v; }
        et[qq * 64 + p] = sacc;
    }
    __syncthreads();
    const int pg = t & 15, jg = t >> 4;
    const int p0 = pg * 4;
    float zn[4];
#pragma unroll
    for (int i = 0; i < 4; ++i) {
        int p = p0 + i;
        zn[i] = ((et[p] + et[64 + p]) + et[128 + p]) + et[192 + p];
    }
    float bestv[4] = {3.0e38f, 3.0e38f, 3.0e38f, 3.0e38f};
    int   besti[4] = {0, 0, 0, 0};
    const int dj = t >> 3, q = t & 7;
    const int sw_st = (q & 3) << 3;
    for (int jt = 0; jt < NCODES / CT; ++jt) {
        const int J0 = jt * CT;
        float acc[4][8];
#pragma unroll
        for (int i = 0; i < 4; ++i)
#pragma unroll
            for (int m = 0; m < 8; ++m) acc[i][m] = 0.f;
        for (int ks = 0; ks < Cdim / KC; ++ks) {
            const int cc0 = ks * KC;
            __syncthreads();
#pragma unroll
            for (int i = 0; i < 4; ++i) {
                const int jrel = dj + 32 * i;
                const float4 v = *reinterpret_cast<const float4*>(
                    embed + (size_t)(J0 + jrel) * Cdim + cc0 + q * 4);
                const int c0 = q * 4;
                const int jsw = jrel ^ sw_st;
                et[(c0 + 0) * CT + jsw] = v.x;
                et[(c0 + 1) * CT + jsw] = v.y;
                et[(c0 + 2) * CT + jsw] = v.z;
                et[(c0 + 3) * CT + jsw] = v.w;
            }
            __syncthreads();
#pragma unroll 4
            for (int c = 0; c < KC; ++c) {
                const float4 zp = *reinterpret_cast<const float4*>(&zt[(cc0 + c) * PTS + p0]);
                const int jb = (jg * 8) ^ (((c >> 2) & 3) << 3);
                const float4 ea = *reinterpret_cast<const float4*>(&et[c * CT + jb]);
                const float4 eb = *reinterpret_cast<const float4*>(&et[c * CT + jb + 4]);
                const float zc[4] = {zp.x, zp.y, zp.z, zp.w};
                const float ec[8] = {ea.x, ea.y, ea.z, ea.w, eb.x, eb.y, eb.z, eb.w};
#pragma unroll
                for (int i = 0; i < 4; ++i)
#pragma unroll
                    for (int m = 0; m < 8; ++m) acc[i][m] += zc[i] * ec[m];
            }
        }
#pragma unroll
        for (int m = 0; m < 8; ++m) {
            const int cid = J0 + jg * 8 + m;
            const float en = enorm[cid];
#pragma unroll
            for (int i = 0; i < 4; ++i) {
                float k1 = zn[i] + en;
                float sc = k1 - 2.0f * acc[i][m];
                if (sc < bestv[i]) { bestv[i] = sc; besti[i] = cid; }
            }
        }
    }
    __syncthreads();
    float* rv = et; int* ri = (int*)(et + 1024); int* idxf = (int*)(et + 2048);
#pragma unroll
    for (int i = 0; i < 4; ++i) { int p = p0 + i; rv[p * 16 + jg] = bestv[i]; ri[p * 16 + jg] = besti[i]; }
    __syncthreads();
    if (t < PTS) {
        int p = t;
        float bv = rv[p * 16]; int bi = ri[p * 16];
        for (int g = 1; g < 16; ++g) {
            float v = rv[p * 16 + g]; int ii = ri[p * 16 + g];
            if (v < bv || (v == bv && ii < bi)) { bv = v; bi = ii; }
        }
        idxf[p] = bi;
        out_idx[n0 + p] = (float)bi;
        atomicAdd(&counts[bi], 1.0f);
    }
    __syncthreads();
    float lsum = 0.f;
    {
        const int p = t & 63, cbase = t >> 6;
        const int myidx = idxf[p];
        const float4* erow4 = reinterpret_cast<const float4*>(embed + (size_t)myidx * Cdim);
        float* ob = out_zq + (size_t)b * Cdim * Ssp + s0 + p;
#pragma unroll 4
        for (int pass = 0; pass < 16; ++pass) {
            int c = cbase * 64 + pass * 4;
            float4 e = erow4[c >> 2];
            ob[(size_t)(c + 0) * Ssp] = e.x;
            ob[(size_t)(c + 1) * Ssp] = e.y;
            ob[(size_t)(c + 2) * Ssp] = e.z;
            ob[(size_t)(c + 3) * Ssp] = e.w;
            float d0 = zt[(c + 0) * PTS + p] - e.x;
            float d1 = zt[(c + 1) * PTS + p] - e.y;
            float d2 = zt[(c + 2) * PTS + p] - e.z;
            float d3 = zt[(c + 3) * PTS + p] - e.w;
            lsum += d0 * d0 + d1 * d1 + d2 * d2 + d3 * d3;
        }
    }
#pragma unroll
    for (int off = 32; off > 0; off >>= 1) lsum += __shfl_down(lsum, off, 64);
    if ((t & 63) == 0) atomicAdd(loss_acc, lsum);
}

// ---------------- finalize ----------------
__global__ __launch_bounds__(1024) void vq_final(const float* __restrict__ counts,
                                                 const float* __restrict__ loss_acc,
                                                 float* __restrict__ out_loss,
                                                 float* __restrict__ out_perp) {
    __shared__ float red[16];
    int t = threadIdx.x;
    float cnt = counts[t];
    float avg = cnt * (1.0f / (float)Npts);
    float term = avg * logf(avg + 1e-10f);
#pragma unroll
    for (int off = 32; off > 0; off >>= 1) term += __shfl_down(term, off, 64);
    if ((t & 63) == 0) red[t >> 6] = term;
    __syncthreads();
    if (t == 0) {
        float s = 0.f;
        for (int i = 0; i < 16; ++i) s += red[i];
        *out_perp = expf(-s);
        *out_loss = BETA * loss_acc[0] * (1.0f / 16777216.0f);
    }
}

extern "C" void kernel_launch(void* const* d_in, const int* in_sizes, int n_in,
                              void* d_out, int out_size, void* d_ws, size_t ws_size,
                              hipStream_t stream) {
    const float* z     = (const float*)d_in[0];
    const float* embed = (const float*)d_in[1];

    float* ws       = (float*)d_ws;
    float* loss_acc = ws;            // [0]
    float* counts   = ws + 64;       // [1024]
    float* enorm    = ws + 2048;     // [1024]

    float* out_zq   = (float*)d_out;
    float* out_idx  = out_zq + (size_t)Npts * Cdim;
    float* out_loss = out_idx + Npts;
    float* out_perp = out_loss + 1;

    hipMemsetAsync(d_ws, 0, 2048 * sizeof(float), stream);
    enorm_kernel<<<NCODES / 256, 256, 0, stream>>>(embed, enorm);

    if (ws_size >= WS_NEED) {
        f16* Bws = (f16*)((char*)d_ws + 65536);
        prep_kernel<<<768, 256, 0, stream>>>(embed, Bws);
        vq_gemm<<<Npts / MT, 512, 0, stream>>>(z, Bws, enorm, out_idx,
                                               loss_acc, counts);
        vq_epi<<<Npts / 256, 256, 0, stream>>>(embed, out_idx, out_zq);
    } else {
        vq_main_fb<<<Npts / PTS, 256, 0, stream>>>(z, embed, enorm, out_zq, out_idx,
                                                   loss_acc, counts);
    }
    vq_final<<<1, 1024, 0, stream>>>(counts, loss_acc, out_loss, out_perp);
}